// Round 4
// baseline (247.102 us; speedup 1.0000x reference)
//
#include <hip/hip_runtime.h>
#include <cfloat>
#include <math.h>

#define E 16
#define DFULL 1024
#define DM 128
#define S 64
#define P 2048
#define B 8
#define C 256
#define W 3
#define H 16
#define RQ 16   /* rows per block chunk */
#define NCH 16  /* row chunks per (e,b) */

typedef __attribute__((ext_vector_type(8))) short short8;
typedef __attribute__((ext_vector_type(4))) float f32x4;
#define MFMA_BF16(a, b, c) __builtin_amdgcn_mfma_f32_16x16x32_bf16((a), (b), (c), 0, 0, 0)

struct RoutesArg { int nb[E][W]; };

// ---------------- host: replicate _expert_routes() exactly ----------------
static void compute_routes(int r[E][W]) {
  float coords[E];
  for (int i = 0; i < E; ++i) {
    double x = (double)i / (double)(E - 1);
    if (x < 1e-06) x = 1e-06;
    if (x > 1.0 - 1e-06) x = 1.0 - 1e-06;
    double val = 0.0, factor = 0.5;
    for (int k = 0; k < 8; ++k) {
      x *= 3.0;
      int d = (int)x;
      x -= (double)d;
      if (d == 2) val += factor;
      factor *= 0.5;
    }
    coords[i] = (float)val;
  }
  for (int e = 0; e < E; ++e) {
    float de[E];
    for (int i = 0; i < E; ++i) de[i] = fabsf(coords[i] - coords[e]);
    bool used[E] = {false};
    for (int w = 0; w < W; ++w) {
      int best = -1; float bd = FLT_MAX;
      for (int i = 0; i < E; ++i)
        if (!used[i] && de[i] < bd) { bd = de[i]; best = i; }  // strict < = stable
      used[best] = true;
      r[e][w] = best;
    }
  }
}

__device__ __forceinline__ unsigned short bfhi(float x) {
  return (unsigned short)(__float_as_uint(x) >> 16);  // truncation split
}
__device__ __forceinline__ float bf2f(unsigned short h) {
  return __uint_as_float(((unsigned)h) << 16);
}
__device__ __forceinline__ float gelu_tanh(float x) {
  float x3 = x * x * x;
  return 0.5f * x * (1.0f + tanhf(0.7978845608028654f * (x + 0.044715f * x3)));
}
__device__ __forceinline__ float sigmoidf_(float x) {
  return 1.0f / (1.0f + __expf(-x));
}

// row max of valid scores: m_v = q_v * (q_v>0 ? max_k : min_k)
__device__ __forceinline__ void calc_m(const float* __restrict__ kmx,
                                       const float* __restrict__ kmn,
                                       const int nbs[3], int b,
                                       const float q[5], float m[5]) {
  #pragma unroll
  for (int v = 0; v < 5; ++v) {
    float KX = -FLT_MAX, KN = FLT_MAX;
    #pragma unroll
    for (int n = 0; n < 3; ++n) {
      int base = ((nbs[n] * 5 + v) * B + b) * NCH;
      for (int k = 0; k < NCH; ++k) {
        KX = fmaxf(KX, kmx[base + k]);
        KN = fminf(KN, kmn[base + k]);
      }
    }
    m[v] = (q[v] > 0.f) ? q[v] * KX : q[v] * KN;
  }
}

// ---------------- K0: dispatch + transposed bf16 weight planes ----------------
__global__ __launch_bounds__(256) void k_setup(
    const float* __restrict__ fp, const float* __restrict__ qw,
    const float* __restrict__ kw, const float* __restrict__ penta,
    const float* __restrict__ temp, const float* __restrict__ vw,
    int* __restrict__ idx, int* __restrict__ counts,
    unsigned short* __restrict__ qkdT_h, unsigned short* __restrict__ qkdT_l,
    unsigned short* __restrict__ vwT_h, unsigned short* __restrict__ vwT_l) {
  int e = blockIdx.x, t = threadIdx.x;
  // ---- dispatch ----
  {
    float lo = (float)e * 0.0625f, hi = (float)(e + 1) * 0.0625f;
    bool last = (e == E - 1);
    int p0 = t * 8;
    int m[8]; int ls = 0;
    #pragma unroll
    for (int k = 0; k < 8; ++k) {
      float f = fp[p0 + k];
      bool mm = (f >= lo) && (last ? (f <= hi) : (f < hi));
      m[k] = mm ? 1 : 0;
      ls += m[k];
    }
    __shared__ int sc[256];
    sc[t] = ls;
    __syncthreads();
    for (int o = 1; o < 256; o <<= 1) {
      int v = (t >= o) ? sc[t - o] : 0;
      __syncthreads();
      sc[t] += v;
      __syncthreads();
    }
    int incl = sc[t];
    int M = sc[255];
    int r = incl - ls;
    #pragma unroll
    for (int k = 0; k < 8; ++k) {
      if (m[k]) {
        if (r < C) idx[e * C + r] = p0 + k;
        r++;
      }
    }
    if (t == 0) counts[e] = (M < C) ? M : C;
  }
  __syncthreads();
  // ---- qkdT (folded penta-norm + 1/T), bf16 hi/lo, [e][c(16)][s] ----
  __shared__ float s_rn[5];
  if (t < 5) {
    const float* pv = penta + (e * 5 + t) * DM;
    float ss = 0.f;
    for (int d = 0; d < DM; ++d) ss += pv[d] * pv[d];
    s_rn[t] = 1.0f / sqrtf(ss);
  }
  __syncthreads();
  float invT = 1.0f / temp[0];
  int s = t & 63, cg = t >> 6;
  for (int c = cg; c < 10; c += 4) {
    int v = c % 5;
    bool isq = (c < 5);
    const float* wrow = (isq ? qw : kw) + ((size_t)e * S + s) * DM;
    const float* pv = penta + (e * 5 + v) * DM;
    float acc = 0.f;
    #pragma unroll
    for (int d4 = 0; d4 < DM / 4; ++d4) {
      float4 a = ((const float4*)wrow)[d4];
      float4 p = ((const float4*)pv)[d4];
      acc += a.x * p.x + a.y * p.y + a.z * p.z + a.w * p.w;
    }
    float val = acc * s_rn[v] * (isq ? invT : 1.0f);
    unsigned short h = bfhi(val), l = bfhi(val - bf2f(h));
    qkdT_h[(e * 16 + c) * 64 + s] = h;
    qkdT_l[(e * 16 + c) * 64 + s] = l;
  }
  for (int c = 10 + cg; c < 16; c += 4) {  // zero-pad c=10..15
    qkdT_h[(e * 16 + c) * 64 + s] = 0;
    qkdT_l[(e * 16 + c) * 64 + s] = 0;
  }
  // ---- vwT bf16 hi/lo, [e][d(128)][s(64)] ----
  const float* vwe = vw + (size_t)e * S * DM;
  for (int u = t; u < S * DM; u += 256) {
    int d = u & 127, ss2 = u >> 7;  // u = ss2*128 + d -> coalesced read
    float f = vwe[u];
    unsigned short h = bfhi(f), l = bfhi(f - bf2f(h));
    vwT_h[(size_t)e * 8192 + d * 64 + ss2] = h;
    vwT_l[(size_t)e * 8192 + d * 64 + ss2] = l;
  }
}

// ---------------- K1: gate + Qa/Ka (MFMA) + Vt (MFMA), 16-row chunks ----------------
__global__ __launch_bounds__(256) void k_p1(
    const float* __restrict__ tokens, const float* __restrict__ alpha,
    const float* __restrict__ gw1, const float* __restrict__ gb1,
    const float* __restrict__ gw2, const float* __restrict__ gb2,
    const unsigned short* __restrict__ qkdT_h, const unsigned short* __restrict__ qkdT_l,
    const unsigned short* __restrict__ vwT_h, const unsigned short* __restrict__ vwT_l,
    const int* __restrict__ idx, const int* __restrict__ counts,
    float* __restrict__ Qa, float* __restrict__ Ka,
    unsigned short* __restrict__ Vt_h, unsigned short* __restrict__ Vt_l,
    float* __restrict__ kmx, float* __restrict__ kmn) {
  int e = blockIdx.x, b = blockIdx.y, rq = blockIdx.z;
  int t = threadIdx.x;
  int Me = counts[e];
  int r0 = rq * RQ;

  if (r0 >= Me) {
    if (t < 5) {
      kmx[((e * 5 + t) * B + b) * NCH + rq] = -FLT_MAX;
      kmn[((e * 5 + t) * B + b) * NCH + rq] = FLT_MAX;
    }
    return;
  }

  __shared__ float s_f[RQ * 65];
  __shared__ __align__(16) unsigned short s_fh[RQ * 72];
  __shared__ __align__(16) unsigned short s_fl[RQ * 72];
  __shared__ float s_gw1[S * H];
  __shared__ float s_gh[RQ * 8 * H];
  __shared__ float s_scl[RQ];
  __shared__ float s_kx[5 * RQ], s_kn[5 * RQ];

  // stage feats (16 rows x 16 float4, 1 f4/thread) and gw1 (256 f4)
  {
    int row = t >> 4, q4 = t & 15;
    int ii = r0 + row;
    int pos = (ii < Me) ? idx[e * C + ii] : idx[e * C];
    const float* trow = tokens + ((size_t)b * P + pos) * DFULL + e * S;
    float4 v4 = ((const float4*)trow)[q4];
    s_f[row * 65 + q4 * 4 + 0] = v4.x;
    s_f[row * 65 + q4 * 4 + 1] = v4.y;
    s_f[row * 65 + q4 * 4 + 2] = v4.z;
    s_f[row * 65 + q4 * 4 + 3] = v4.w;
    ((float4*)s_gw1)[t] = ((const float4*)(gw1 + (size_t)e * S * H))[t];
  }
  __syncthreads();

  // gate partials: 8 threads per row, 8 s each
  if (t < 128) {
    int row = t >> 3, sq = t & 7;
    float hh[H];
    #pragma unroll
    for (int j = 0; j < H; ++j) hh[j] = 0.f;
    #pragma unroll
    for (int k = 0; k < 8; ++k) {
      int s = sq * 8 + k;
      float fs = s_f[row * 65 + s];
      const float* gr = s_gw1 + s * H;
      #pragma unroll
      for (int j = 0; j < H; ++j) hh[j] += fs * gr[j];
    }
    #pragma unroll
    for (int j = 0; j < H; ++j) s_gh[(row * 8 + sq) * H + j] = hh[j];
  }
  __syncthreads();
  if (t < RQ) {
    float z = gb2[e];
    #pragma unroll
    for (int j = 0; j < H; ++j) {
      float hj = gb1[e * H + j];
      #pragma unroll
      for (int p = 0; p < 8; ++p) hj += s_gh[(t * 8 + p) * H + j];
      z += gelu_tanh(hj) * gw2[e * H + j];
    }
    float aw = sigmoidf_(alpha[e]);
    s_scl[t] = sigmoidf_(z) * aw + (1.0f - aw);
  }
  __syncthreads();
  // scale + split-bf16 convert (4 elems/thread)
  {
    int row = t >> 4, s0 = (t & 15) * 4;
    float sc = s_scl[row];
    #pragma unroll
    for (int k = 0; k < 4; ++k) {
      float f = s_f[row * 65 + s0 + k] * sc;
      unsigned short h = bfhi(f), l = bfhi(f - bf2f(h));
      s_fh[row * 72 + s0 + k] = h;
      s_fl[row * 72 + s0 + k] = l;
    }
  }
  __syncthreads();

  int L = t & 63, wv = t >> 6, quad = L >> 4, col = L & 15;

  // V = feats @ v_w via MFMA; D stored transposed bf16 hi/lo -> Vt[e][b][d][row]
  {
    const unsigned short* vTh = vwT_h + (size_t)e * 8192;
    const unsigned short* vTl = vwT_l + (size_t)e * 8192;
    f32x4 va0 = {0.f, 0.f, 0.f, 0.f}, va1 = {0.f, 0.f, 0.f, 0.f};
    int d0 = wv * 32 + col, d1 = d0 + 16;
    #pragma unroll
    for (int kc = 0; kc < 2; ++kc) {
      int ko = kc * 32 + quad * 8;
      short8 ah = *(const short8*)(s_fh + col * 72 + ko);
      short8 al = *(const short8*)(s_fl + col * 72 + ko);
      short8 bh0 = *(const short8*)(vTh + d0 * 64 + ko);
      short8 bl0 = *(const short8*)(vTl + d0 * 64 + ko);
      short8 bh1 = *(const short8*)(vTh + d1 * 64 + ko);
      short8 bl1 = *(const short8*)(vTl + d1 * 64 + ko);
      va0 = MFMA_BF16(ah, bh0, va0);
      va0 = MFMA_BF16(ah, bl0, va0);
      va0 = MFMA_BF16(al, bh0, va0);
      va1 = MFMA_BF16(ah, bh1, va1);
      va1 = MFMA_BF16(ah, bl1, va1);
      va1 = MFMA_BF16(al, bh1, va1);
    }
    #pragma unroll
    for (int reg = 0; reg < 4; ++reg) {
      int row = quad * 4 + reg;
      int ii = r0 + row;
      if (ii < Me) {
        size_t a0 = ((size_t)(e * B + b) * DM + d0) * C + ii;
        size_t a1 = ((size_t)(e * B + b) * DM + d1) * C + ii;
        float f0 = va0[reg];
        unsigned short h0 = bfhi(f0), l0 = bfhi(f0 - bf2f(h0));
        Vt_h[a0] = h0; Vt_l[a0] = l0;
        float f1 = va1[reg];
        unsigned short h1 = bfhi(f1), l1 = bfhi(f1 - bf2f(h1));
        Vt_h[a1] = h1; Vt_l[a1] = l1;
      }
    }
  }

  // Qa/Ka = feats @ qkd^T via MFMA (wave 0 only; N=16 covers c=0..9 + pad)
  if (wv == 0) {
    const unsigned short* qTh = qkdT_h + e * 16 * 64;
    const unsigned short* qTl = qkdT_l + e * 16 * 64;
    f32x4 qa = {0.f, 0.f, 0.f, 0.f};
    #pragma unroll
    for (int kc = 0; kc < 2; ++kc) {
      int ko = kc * 32 + quad * 8;
      short8 ah = *(const short8*)(s_fh + col * 72 + ko);
      short8 al = *(const short8*)(s_fl + col * 72 + ko);
      short8 bh = *(const short8*)(qTh + col * 64 + ko);
      short8 bl = *(const short8*)(qTl + col * 64 + ko);
      qa = MFMA_BF16(ah, bh, qa);
      qa = MFMA_BF16(ah, bl, qa);
      qa = MFMA_BF16(al, bh, qa);
    }
    #pragma unroll
    for (int reg = 0; reg < 4; ++reg) {
      int row = quad * 4 + reg;
      int ii = r0 + row;
      float val = qa[reg];
      if (col < 5) {
        if (ii < Me) Qa[((e * 5 + col) * B + b) * C + ii] = val;
      } else if (col < 10) {
        int v = col - 5;
        if (ii < Me) Ka[((e * 5 + v) * B + b) * C + ii] = val;
        s_kx[v * RQ + row] = (ii < Me) ? val : -FLT_MAX;
        s_kn[v * RQ + row] = (ii < Me) ? val : FLT_MAX;
      }
    }
  }
  __syncthreads();
  if (t < 5) {
    float mx = -FLT_MAX, mn = FLT_MAX;
    for (int r = 0; r < RQ; ++r) {
      mx = fmaxf(mx, s_kx[t * RQ + r]);
      mn = fminf(mn, s_kn[t * RQ + r]);
    }
    kmx[((e * 5 + t) * B + b) * NCH + rq] = mx;
    kmn[((e * 5 + t) * B + b) * NCH + rq] = mn;
  }
}

// ---------------- K2: l-pass + w (split-bf16) + MFMA vs global Vt ----------------
__global__ __launch_bounds__(256) void k_p2v(
    const float* __restrict__ Qa, const float* __restrict__ Ka,
    const unsigned short* __restrict__ Vt_h, const unsigned short* __restrict__ Vt_l,
    const float* __restrict__ kmx, const float* __restrict__ kmn,
    const int* __restrict__ idx, const int* __restrict__ counts,
    const float* __restrict__ fusw, float* __restrict__ out, RoutesArg R) {
  int e = blockIdx.x, b = blockIdx.y, rq = blockIdx.z;
  int t = threadIdx.x;
  int Me = counts[e];
  int r0 = rq * RQ;
  if (r0 >= Me) return;

  __shared__ float s_ka[3 * 5 * C];                      // 15 KB
  __shared__ __align__(16) unsigned short s_wh[RQ * 264];
  __shared__ __align__(16) unsigned short s_wl[RQ * 264];
  __shared__ float s_lp[16 * 5 * RQ];                    // 5 KB

  int nbs[3] = {R.nb[e][0], R.nb[e][1], R.nb[e][2]};
  int Mns[3] = {counts[nbs[0]], counts[nbs[1]], counts[nbs[2]]};
  int row = t & 15, jq = t >> 4;
  int ii = r0 + row;

  float q[5], m[5];
  #pragma unroll
  for (int v = 0; v < 5; ++v) q[v] = Qa[((e * 5 + v) * B + b) * C + ii];
  calc_m(kmx, kmn, nbs, b, q, m);

  // stage all 3 neighbors' Ka (coalesced)
  for (int u = t; u < 3 * 5 * C; u += 256) {
    int n = u / (5 * C);
    int rem = u - n * 5 * C;
    int v = rem >> 8, j = rem & 255;
    s_ka[u] = Ka[((size_t)(nbs[n] * 5 + v) * B + b) * C + j];
  }
  __syncthreads();

  // l-pass: 16-way j split per row
  float lp[5] = {0.f, 0.f, 0.f, 0.f, 0.f};
  for (int n = 0; n < 3; ++n) {
    int Mn = Mns[n];
    const float* kb = s_ka + n * 5 * C;
    for (int j = jq; j < Mn; j += 16) {
      #pragma unroll
      for (int v = 0; v < 5; ++v) lp[v] += __expf(q[v] * kb[v * C + j] - m[v]);
    }
  }
  #pragma unroll
  for (int v = 0; v < 5; ++v) s_lp[(jq * 5 + v) * RQ + row] = lp[v];
  __syncthreads();

  // wdir = softmax(fusion_w); cl = wdir / l
  float fw[5];
  #pragma unroll
  for (int v = 0; v < 5; ++v) fw[v] = fusw[v];
  float fmx = fw[0];
  #pragma unroll
  for (int v = 1; v < 5; ++v) fmx = fmaxf(fmx, fw[v]);
  float fsum = 0.f;
  #pragma unroll
  for (int v = 0; v < 5; ++v) { fw[v] = __expf(fw[v] - fmx); fsum += fw[v]; }
  float cl[5];
  #pragma unroll
  for (int v = 0; v < 5; ++v) {
    float l = 0.f;
    #pragma unroll
    for (int g = 0; g < 16; ++g) l += s_lp[(g * 5 + v) * RQ + row];
    cl[v] = (fw[v] / fsum) / l;
  }

  int L = t & 63, wv = t >> 6, quad = L >> 4, col = L & 15;
  f32x4 acc0 = {0.f, 0.f, 0.f, 0.f}, acc1 = {0.f, 0.f, 0.f, 0.f};

  for (int n = 0; n < 3; ++n) {
    int ne = nbs[n], Mn = Mns[n];
    __syncthreads();  // protect s_wh/s_wl from previous MFMA reads
    // phase A: combined weights, split-bf16, each (row,jj) exp'd once
    const float* kb = s_ka + n * 5 * C;
    for (int k = 0; k < 16; ++k) {
      int jj = jq * 16 + k;
      float ww = 0.f;
      if (jj < Mn) {
        #pragma unroll
        for (int v = 0; v < 5; ++v) ww += cl[v] * __expf(q[v] * kb[v * C + jj] - m[v]);
      }
      unsigned short h = bfhi(ww), l = bfhi(ww - bf2f(h));
      s_wh[row * 264 + jj] = h;
      s_wl[row * 264 + jj] = l;
    }
    __syncthreads();
    // MFMA: A = w tile (LDS), B = Vt (global, L2-resident)
    const unsigned short* vTh = Vt_h + (size_t)(ne * B + b) * DM * C;
    const unsigned short* vTl = Vt_l + (size_t)(ne * B + b) * DM * C;
    int d0 = wv * 32 + col, d1 = d0 + 16;
    int kcN = (Mn + 31) >> 5;
    for (int kc = 0; kc < kcN; ++kc) {
      int ko = kc * 32 + quad * 8;
      short8 ah = *(const short8*)(s_wh + col * 264 + ko);
      short8 al = *(const short8*)(s_wl + col * 264 + ko);
      short8 bh0 = *(const short8*)(vTh + (size_t)d0 * C + ko);
      short8 bl0 = *(const short8*)(vTl + (size_t)d0 * C + ko);
      short8 bh1 = *(const short8*)(vTh + (size_t)d1 * C + ko);
      short8 bl1 = *(const short8*)(vTl + (size_t)d1 * C + ko);
      acc0 = MFMA_BF16(ah, bh0, acc0);
      acc0 = MFMA_BF16(ah, bl0, acc0);
      acc0 = MFMA_BF16(al, bh0, acc0);
      acc1 = MFMA_BF16(ah, bh1, acc1);
      acc1 = MFMA_BF16(ah, bl1, acc1);
      acc1 = MFMA_BF16(al, bh1, acc1);
    }
  }

  // store: D rows quad*4+reg, cols d0/d1; disjoint across blocks
  #pragma unroll
  for (int reg = 0; reg < 4; ++reg) {
    int rr = quad * 4 + reg;
    int iw = r0 + rr;
    if (iw < Me) {
      int pos = idx[e * C + iw];
      float* orow = out + ((size_t)b * P + pos) * DM;
      orow[wv * 32 + col] = acc0[reg];
      orow[wv * 32 + 16 + col] = acc1[reg];
    }
  }
}

// ---------------- launch ----------------
extern "C" void kernel_launch(void* const* d_in, const int* in_sizes, int n_in,
                              void* d_out, int out_size, void* d_ws, size_t ws_size,
                              hipStream_t stream) {
  const float* tokens = (const float*)d_in[0];
  const float* fingerprints = (const float*)d_in[1];
  const float* alpha = (const float*)d_in[2];
  const float* gw1 = (const float*)d_in[3];
  const float* gb1 = (const float*)d_in[4];
  const float* gw2 = (const float*)d_in[5];
  const float* gb2 = (const float*)d_in[6];
  const float* qw = (const float*)d_in[7];
  const float* kw = (const float*)d_in[8];
  const float* vw = (const float*)d_in[9];
  const float* penta = (const float*)d_in[10];
  const float* fusw = (const float*)d_in[11];
  const float* temp = (const float*)d_in[12];
  float* out = (float*)d_out;

  float* ws = (float*)d_ws;
  float* Qa = ws;                                   // E*5*B*C = 163840 f
  float* Ka = Qa + (size_t)E * 5 * B * C;           // 163840 f
  float* kmx = Ka + (size_t)E * 5 * B * C;          // E*5*B*NCH = 10240 f
  float* kmn = kmx + (size_t)E * 5 * B * NCH;       // 10240 f
  unsigned short* qkdT_h = (unsigned short*)(kmn + (size_t)E * 5 * B * NCH);
  unsigned short* qkdT_l = qkdT_h + (size_t)E * 16 * 64;   // 16384 u16 each
  unsigned short* vwT_h = qkdT_l + (size_t)E * 16 * 64;    // 131072 u16 each
  unsigned short* vwT_l = vwT_h + (size_t)E * S * DM;
  unsigned short* Vt_h = vwT_l + (size_t)E * S * DM;       // 4194304 u16 each
  unsigned short* Vt_l = Vt_h + (size_t)E * B * DM * C;
  int* idx = (int*)(Vt_l + (size_t)E * B * DM * C);        // E*C ints
  int* counts = idx + (size_t)E * C;                       // E ints

  RoutesArg R;
  compute_routes(R.nb);

  hipMemsetAsync(d_out, 0, (size_t)out_size * sizeof(float), stream);
  k_setup<<<dim3(E), dim3(256), 0, stream>>>(fingerprints, qw, kw, penta, temp, vw,
                                             idx, counts, qkdT_h, qkdT_l, vwT_h, vwT_l);
  k_p1<<<dim3(E, B, NCH), dim3(256), 0, stream>>>(tokens, alpha, gw1, gb1, gw2, gb2,
                                                  qkdT_h, qkdT_l, vwT_h, vwT_l,
                                                  idx, counts, Qa, Ka, Vt_h, Vt_l,
                                                  kmx, kmn);
  k_p2v<<<dim3(E, B, NCH), dim3(256), 0, stream>>>(Qa, Ka, Vt_h, Vt_l, kmx, kmn,
                                                   idx, counts, fusw, out, R);
}

// Round 5
// 208.991 us; speedup vs baseline: 1.1824x; 1.1824x over previous
//
#include <hip/hip_runtime.h>
#include <cfloat>
#include <math.h>

#define E 16
#define DFULL 1024
#define DM 128
#define S 64
#define P 2048
#define B 8
#define C 256
#define W 3
#define H 16
#define RQ 16   /* rows per block chunk */
#define NCH 16  /* row chunks per (e,b) */
#define LOG2E 1.4426950408889634f

typedef __attribute__((ext_vector_type(8))) short short8;
typedef __attribute__((ext_vector_type(4))) float f32x4;
#define MFMA_BF16(a, b, c) __builtin_amdgcn_mfma_f32_16x16x32_bf16((a), (b), (c), 0, 0, 0)

struct RoutesArg { int nb[E][W]; };

// ---------------- host: replicate _expert_routes() exactly ----------------
static void compute_routes(int r[E][W]) {
  float coords[E];
  for (int i = 0; i < E; ++i) {
    double x = (double)i / (double)(E - 1);
    if (x < 1e-06) x = 1e-06;
    if (x > 1.0 - 1e-06) x = 1.0 - 1e-06;
    double val = 0.0, factor = 0.5;
    for (int k = 0; k < 8; ++k) {
      x *= 3.0;
      int d = (int)x;
      x -= (double)d;
      if (d == 2) val += factor;
      factor *= 0.5;
    }
    coords[i] = (float)val;
  }
  for (int e = 0; e < E; ++e) {
    float de[E];
    for (int i = 0; i < E; ++i) de[i] = fabsf(coords[i] - coords[e]);
    bool used[E] = {false};
    for (int w = 0; w < W; ++w) {
      int best = -1; float bd = FLT_MAX;
      for (int i = 0; i < E; ++i)
        if (!used[i] && de[i] < bd) { bd = de[i]; best = i; }  // strict < = stable
      used[best] = true;
      r[e][w] = best;
    }
  }
}

__device__ __forceinline__ unsigned short bfhi(float x) {
  return (unsigned short)(__float_as_uint(x) >> 16);  // truncation split
}
__device__ __forceinline__ float bf2f(unsigned short h) {
  return __uint_as_float(((unsigned)h) << 16);
}
__device__ __forceinline__ float gelu_tanh(float x) {
  float x3 = x * x * x;
  return 0.5f * x * (1.0f + tanhf(0.7978845608028654f * (x + 0.044715f * x3)));
}
__device__ __forceinline__ float sigmoidf_(float x) {
  return 1.0f / (1.0f + __expf(-x));
}

// ---------------- K0: dispatch + bf16 weight planes (grid E x 2) ----------------
__global__ __launch_bounds__(256) void k_setup(
    const float* __restrict__ fp, const float* __restrict__ qw,
    const float* __restrict__ kw, const float* __restrict__ penta,
    const float* __restrict__ temp, const float* __restrict__ vw,
    int* __restrict__ idx, int* __restrict__ counts,
    unsigned short* __restrict__ qkdT_h, unsigned short* __restrict__ qkdT_l,
    unsigned short* __restrict__ vwT_h, unsigned short* __restrict__ vwT_l) {
  int e = blockIdx.x, t = threadIdx.x;
  if (blockIdx.y == 1) {
    // vwT: [e][d(128)][s(64)] hi/lo; writes coalesced (u = d*64+s, s fastest)
    const float* vwe = vw + (size_t)e * S * DM;
    for (int u = t; u < S * DM; u += 256) {
      int d = u >> 6, s = u & 63;
      float f = vwe[(size_t)s * DM + d];
      unsigned short h = bfhi(f), l = bfhi(f - bf2f(h));
      vwT_h[(size_t)e * 8192 + u] = h;
      vwT_l[(size_t)e * 8192 + u] = l;
    }
    return;
  }
  // ---- dispatch ----
  {
    float lo = (float)e * 0.0625f, hi = (float)(e + 1) * 0.0625f;
    bool last = (e == E - 1);
    int p0 = t * 8;
    int m[8]; int ls = 0;
    #pragma unroll
    for (int k = 0; k < 8; ++k) {
      float f = fp[p0 + k];
      bool mm = (f >= lo) && (last ? (f <= hi) : (f < hi));
      m[k] = mm ? 1 : 0;
      ls += m[k];
    }
    __shared__ int sc[256];
    sc[t] = ls;
    __syncthreads();
    for (int o = 1; o < 256; o <<= 1) {
      int v = (t >= o) ? sc[t - o] : 0;
      __syncthreads();
      sc[t] += v;
      __syncthreads();
    }
    int incl = sc[t];
    int M = sc[255];
    int r = incl - ls;
    #pragma unroll
    for (int k = 0; k < 8; ++k) {
      if (m[k]) {
        if (r < C) idx[e * C + r] = p0 + k;
        r++;
      }
    }
    if (t == 0) counts[e] = (M < C) ? M : C;
  }
  __syncthreads();
  // ---- qkdT (folded penta-norm + 1/T), [e][c(16)][s(64)] hi/lo ----
  __shared__ float s_rn[5];
  if (t < 5) {
    const float* pv = penta + (e * 5 + t) * DM;
    float ss = 0.f;
    for (int d = 0; d < DM; ++d) ss += pv[d] * pv[d];
    s_rn[t] = 1.0f / sqrtf(ss);
  }
  __syncthreads();
  float invT = 1.0f / temp[0];
  int s = t & 63, cg = t >> 6;
  for (int c = cg; c < 10; c += 4) {
    int v = c % 5;
    bool isq = (c < 5);
    const float* wrow = (isq ? qw : kw) + ((size_t)e * S + s) * DM;
    const float* pv = penta + (e * 5 + v) * DM;
    float acc = 0.f;
    #pragma unroll
    for (int d4 = 0; d4 < DM / 4; ++d4) {
      float4 a = ((const float4*)wrow)[d4];
      float4 p = ((const float4*)pv)[d4];
      acc += a.x * p.x + a.y * p.y + a.z * p.z + a.w * p.w;
    }
    float val = acc * s_rn[v] * (isq ? invT : 1.0f);
    unsigned short h = bfhi(val), l = bfhi(val - bf2f(h));
    qkdT_h[(e * 16 + c) * 64 + s] = h;
    qkdT_l[(e * 16 + c) * 64 + s] = l;
  }
  for (int c = 10 + cg; c < 16; c += 4) {  // zero-pad c=10..15
    qkdT_h[(e * 16 + c) * 64 + s] = 0;
    qkdT_l[(e * 16 + c) * 64 + s] = 0;
  }
}

// ---------------- K1: gate + Qa/Ka (MFMA) + Vt slab (MFMA) ----------------
__global__ __launch_bounds__(256) void k_p1(
    const float* __restrict__ tokens, const float* __restrict__ alpha,
    const float* __restrict__ gw1, const float* __restrict__ gb1,
    const float* __restrict__ gw2, const float* __restrict__ gb2,
    const unsigned short* __restrict__ qkdT_h, const unsigned short* __restrict__ qkdT_l,
    const unsigned short* __restrict__ vwT_h, const unsigned short* __restrict__ vwT_l,
    const int* __restrict__ idx, const int* __restrict__ counts,
    float* __restrict__ Qa, float* __restrict__ Ka,
    unsigned short* __restrict__ Vt_h, unsigned short* __restrict__ Vt_l,
    float* __restrict__ kmx, float* __restrict__ kmn) {
  int e = blockIdx.x, b = blockIdx.y, rq = blockIdx.z;
  int t = threadIdx.x;
  int Me = counts[e];
  int r0 = rq * RQ;

  if (r0 >= Me) {
    if (t < 5) {
      kmx[((e * 5 + t) * B + b) * NCH + rq] = -FLT_MAX;
      kmn[((e * 5 + t) * B + b) * NCH + rq] = FLT_MAX;
    }
    return;
  }

  __shared__ float s_f[RQ * 65];
  __shared__ __align__(16) unsigned short s_fh[RQ * 72];
  __shared__ __align__(16) unsigned short s_fl[RQ * 72];
  __shared__ float s_gw1[S * H];
  __shared__ float s_gh[RQ * 8 * H];
  __shared__ float s_scl[RQ];
  __shared__ float s_kx[5 * RQ], s_kn[5 * RQ];
  __shared__ __align__(16) unsigned short s_vth[DM * 16];  // [d][row] slab
  __shared__ __align__(16) unsigned short s_vtl[DM * 16];

  // stage feats (16 rows x 16 float4) and gw1 (256 f4)
  {
    int row = t >> 4, q4 = t & 15;
    int ii = r0 + row;
    int pos = (ii < Me) ? idx[e * C + ii] : idx[e * C];
    const float* trow = tokens + ((size_t)b * P + pos) * DFULL + e * S;
    float4 v4 = ((const float4*)trow)[q4];
    s_f[row * 65 + q4 * 4 + 0] = v4.x;
    s_f[row * 65 + q4 * 4 + 1] = v4.y;
    s_f[row * 65 + q4 * 4 + 2] = v4.z;
    s_f[row * 65 + q4 * 4 + 3] = v4.w;
    ((float4*)s_gw1)[t] = ((const float4*)(gw1 + (size_t)e * S * H))[t];
  }
  __syncthreads();

  // gate partials: 8 threads per row, 8 s each
  if (t < 128) {
    int row = t >> 3, sq = t & 7;
    float hh[H];
    #pragma unroll
    for (int j = 0; j < H; ++j) hh[j] = 0.f;
    #pragma unroll
    for (int k = 0; k < 8; ++k) {
      int s = sq * 8 + k;
      float fs = s_f[row * 65 + s];
      const float* gr = s_gw1 + s * H;
      #pragma unroll
      for (int j = 0; j < H; ++j) hh[j] += fs * gr[j];
    }
    #pragma unroll
    for (int j = 0; j < H; ++j) s_gh[(row * 8 + sq) * H + j] = hh[j];
  }
  __syncthreads();
  if (t < RQ) {
    float z = gb2[e];
    #pragma unroll
    for (int j = 0; j < H; ++j) {
      float hj = gb1[e * H + j];
      #pragma unroll
      for (int p = 0; p < 8; ++p) hj += s_gh[(t * 8 + p) * H + j];
      z += gelu_tanh(hj) * gw2[e * H + j];
    }
    float aw = sigmoidf_(alpha[e]);
    s_scl[t] = sigmoidf_(z) * aw + (1.0f - aw);
  }
  __syncthreads();
  // scale + split-bf16 convert (4 elems/thread)
  {
    int row = t >> 4, s0 = (t & 15) * 4;
    float sc = s_scl[row];
    #pragma unroll
    for (int k = 0; k < 4; ++k) {
      float f = s_f[row * 65 + s0 + k] * sc;
      unsigned short h = bfhi(f), l = bfhi(f - bf2f(h));
      s_fh[row * 72 + s0 + k] = h;
      s_fl[row * 72 + s0 + k] = l;
    }
  }
  __syncthreads();

  int L = t & 63, wv = t >> 6, quad = L >> 4, col = L & 15;

  // V = feats @ v_w via MFMA; transpose through LDS into [d][row] slab
  {
    const unsigned short* vTh = vwT_h + (size_t)e * 8192;
    const unsigned short* vTl = vwT_l + (size_t)e * 8192;
    f32x4 va0 = {0.f, 0.f, 0.f, 0.f}, va1 = {0.f, 0.f, 0.f, 0.f};
    int d0 = wv * 32 + col, d1 = d0 + 16;
    #pragma unroll
    for (int kc = 0; kc < 2; ++kc) {
      int ko = kc * 32 + quad * 8;
      short8 ah = *(const short8*)(s_fh + col * 72 + ko);
      short8 al = *(const short8*)(s_fl + col * 72 + ko);
      short8 bh0 = *(const short8*)(vTh + d0 * 64 + ko);
      short8 bl0 = *(const short8*)(vTl + d0 * 64 + ko);
      short8 bh1 = *(const short8*)(vTh + d1 * 64 + ko);
      short8 bl1 = *(const short8*)(vTl + d1 * 64 + ko);
      va0 = MFMA_BF16(ah, bh0, va0);
      va0 = MFMA_BF16(ah, bl0, va0);
      va0 = MFMA_BF16(al, bh0, va0);
      va1 = MFMA_BF16(ah, bh1, va1);
      va1 = MFMA_BF16(ah, bl1, va1);
      va1 = MFMA_BF16(al, bh1, va1);
    }
    #pragma unroll
    for (int reg = 0; reg < 4; ++reg) {
      int row = quad * 4 + reg;
      float f0 = va0[reg];
      unsigned short h0 = bfhi(f0), l0 = bfhi(f0 - bf2f(h0));
      s_vth[d0 * 16 + row] = h0;
      s_vtl[d0 * 16 + row] = l0;
      float f1 = va1[reg];
      unsigned short h1 = bfhi(f1), l1 = bfhi(f1 - bf2f(h1));
      s_vth[d1 * 16 + row] = h1;
      s_vtl[d1 * 16 + row] = l1;
    }
  }

  // Qa/Ka = feats @ qkd^T via MFMA (wave 0; N=16 covers c=0..9 + pad)
  if (wv == 0) {
    const unsigned short* qTh = qkdT_h + e * 16 * 64;
    const unsigned short* qTl = qkdT_l + e * 16 * 64;
    f32x4 qa = {0.f, 0.f, 0.f, 0.f};
    #pragma unroll
    for (int kc = 0; kc < 2; ++kc) {
      int ko = kc * 32 + quad * 8;
      short8 ah = *(const short8*)(s_fh + col * 72 + ko);
      short8 al = *(const short8*)(s_fl + col * 72 + ko);
      short8 bh = *(const short8*)(qTh + col * 64 + ko);
      short8 bl = *(const short8*)(qTl + col * 64 + ko);
      qa = MFMA_BF16(ah, bh, qa);
      qa = MFMA_BF16(ah, bl, qa);
      qa = MFMA_BF16(al, bh, qa);
    }
    #pragma unroll
    for (int reg = 0; reg < 4; ++reg) {
      int row = quad * 4 + reg;
      int ii = r0 + row;
      float val = qa[reg];
      if (col < 5) {
        if (ii < Me) Qa[((e * 5 + col) * B + b) * C + ii] = val;
      } else if (col < 10) {
        int v = col - 5;
        if (ii < Me) Ka[((e * 5 + v) * B + b) * C + ii] = val;
        s_kx[v * RQ + row] = (ii < Me) ? val : -FLT_MAX;
        s_kn[v * RQ + row] = (ii < Me) ? val : FLT_MAX;
      }
    }
  }
  __syncthreads();
  if (t < 5) {
    float mx = -FLT_MAX, mn = FLT_MAX;
    for (int r = 0; r < RQ; ++r) {
      mx = fmaxf(mx, s_kx[t * RQ + r]);
      mn = fminf(mn, s_kn[t * RQ + r]);
    }
    kmx[((e * 5 + t) * B + b) * NCH + rq] = mx;
    kmn[((e * 5 + t) * B + b) * NCH + rq] = mn;
  }
  // Vt slab store: [e][b][jt=rq][d][16] -- fully coalesced
  {
    size_t base = ((size_t)(e * B + b) * 16 + rq) * (DM * 16);
    int off = t * 8;
    *(short8*)(Vt_h + base + off) = *(const short8*)(s_vth + off);
    *(short8*)(Vt_l + base + off) = *(const short8*)(s_vtl + off);
  }
}

// ---------------- K2: l-pass + w (short8 writes) + MFMA vs slab Vt ----------------
__global__ __launch_bounds__(256) void k_p2v(
    const float* __restrict__ Qa, const float* __restrict__ Ka,
    const unsigned short* __restrict__ Vt_h, const unsigned short* __restrict__ Vt_l,
    const float* __restrict__ kmx, const float* __restrict__ kmn,
    const int* __restrict__ idx, const int* __restrict__ counts,
    const float* __restrict__ fusw, float* __restrict__ out, RoutesArg R) {
  int e = blockIdx.x, b = blockIdx.y, rq = blockIdx.z;
  int t = threadIdx.x;
  int Me = counts[e];
  int r0 = rq * RQ;
  if (r0 >= Me) return;

  __shared__ float s_ka[3 * 5 * C];                        // 15360 B
  __shared__ __align__(16) unsigned short s_wh[RQ * 264];  // 8448 B
  __shared__ __align__(16) unsigned short s_wl[RQ * 264];
  __shared__ float s_lp[16 * 5 * RQ];                      // 5120 B
  __shared__ float s_KX[5], s_KN[5];
  __shared__ float s_l[5 * RQ];
  float* s_red = (float*)s_wh;  // overlay: 480 floats, dead before phase A

  int nbs[3] = {R.nb[e][0], R.nb[e][1], R.nb[e][2]};
  int Mns[3] = {counts[nbs[0]], counts[nbs[1]], counts[nbs[2]]};
  int row = t & 15, jq = t >> 4;
  int ii = r0 + row;

  // stage Ka (3 neighbors, coalesced) + kmx/kmn (1 load/thread)
  for (int u = t; u < 3 * 5 * C; u += 256) {
    int n = u / (5 * C);
    int rem = u - n * 5 * C;
    int v = rem >> 8, j = rem & 255;
    s_ka[u] = Ka[(((size_t)nbs[n] * 5 + v) * B + b) * C + j];
  }
  if (t < 240) {
    int v = t / 48, rr = t % 48, n = rr >> 4, k = rr & 15;
    int base = ((nbs[n] * 5 + v) * B + b) * NCH + k;
    s_red[t] = kmx[base];
    s_red[240 + t] = kmn[base];
  }
  __syncthreads();
  if (t < 5) {
    float KX = -FLT_MAX, KN = FLT_MAX;
    for (int u = 0; u < 48; ++u) {
      KX = fmaxf(KX, s_red[t * 48 + u]);
      KN = fminf(KN, s_red[240 + t * 48 + u]);
    }
    s_KX[t] = KX; s_KN[t] = KN;
  }
  __syncthreads();

  // per-row q2/m2 (exact row max of scores, log2e-folded)
  float q2[5], m2[5];
  #pragma unroll
  for (int v = 0; v < 5; ++v) {
    float qv = Qa[(((size_t)e * 5 + v) * B + b) * C + ii];
    q2[v] = qv * LOG2E;
    m2[v] = ((qv > 0.f) ? qv * s_KX[v] : qv * s_KN[v]) * LOG2E;
  }

  // l-pass: 16-way j split per row
  float lp[5] = {0.f, 0.f, 0.f, 0.f, 0.f};
  for (int n = 0; n < 3; ++n) {
    int Mn = Mns[n];
    const float* kb = s_ka + n * 5 * C;
    for (int j = jq; j < Mn; j += 16) {
      #pragma unroll
      for (int v = 0; v < 5; ++v)
        lp[v] += exp2f(fmaf(q2[v], kb[v * C + j], -m2[v]));
    }
  }
  #pragma unroll
  for (int v = 0; v < 5; ++v) s_lp[(jq * 5 + v) * RQ + row] = lp[v];
  __syncthreads();
  if (t < 80) {
    int v = t >> 4, rw = t & 15;
    float l = 0.f;
    #pragma unroll
    for (int g = 0; g < 16; ++g) l += s_lp[(g * 5 + v) * RQ + rw];
    s_l[v * RQ + rw] = l;
  }
  __syncthreads();

  // c2 = log2(wdir_v / l) - m2  (fold cl into exp2 arg)
  float fw[5];
  #pragma unroll
  for (int v = 0; v < 5; ++v) fw[v] = fusw[v];
  float fmx = fw[0];
  #pragma unroll
  for (int v = 1; v < 5; ++v) fmx = fmaxf(fmx, fw[v]);
  float fsum = 0.f;
  #pragma unroll
  for (int v = 0; v < 5; ++v) { fw[v] = __expf(fw[v] - fmx); fsum += fw[v]; }
  float c2[5];
  #pragma unroll
  for (int v = 0; v < 5; ++v) {
    float cl = (fw[v] / fsum) / s_l[v * RQ + row];
    c2[v] = __log2f(cl) - m2[v];
  }

  int L = t & 63, wv = t >> 6, quad = L >> 4, col = L & 15;
  int d0 = wv * 32 + col, d1 = d0 + 16;
  f32x4 acc0 = {0.f, 0.f, 0.f, 0.f}, acc1 = {0.f, 0.f, 0.f, 0.f};

  for (int n = 0; n < 3; ++n) {
    int ne = nbs[n], Mn = Mns[n];
    const float* kb = s_ka + n * 5 * C;
    __syncthreads();  // previous neighbor's MFMA reads of s_w done
    // phase A: combined weights, 8 per short8 register, b128 writes
    #pragma unroll
    for (int h8 = 0; h8 < 2; ++h8) {
      short8 wh8, wl8;
      #pragma unroll
      for (int k2 = 0; k2 < 8; ++k2) {
        int jj = jq * 16 + h8 * 8 + k2;
        float ww = 0.f;
        if (jj < Mn) {
          #pragma unroll
          for (int v = 0; v < 5; ++v)
            ww += exp2f(fmaf(q2[v], kb[v * C + jj], c2[v]));
        }
        unsigned short h = bfhi(ww), l = bfhi(ww - bf2f(h));
        wh8[k2] = (short)h;
        wl8[k2] = (short)l;
      }
      *(short8*)(s_wh + row * 264 + jq * 16 + h8 * 8) = wh8;
      *(short8*)(s_wl + row * 264 + jq * 16 + h8 * 8) = wl8;
    }
    __syncthreads();
    // phase B: MFMA, A = w (LDS), B = Vt slabs (global, line-perfect)
    const unsigned short* vbh = Vt_h + (size_t)(ne * B + b) * (DM * C);
    const unsigned short* vbl = Vt_l + (size_t)(ne * B + b) * (DM * C);
    int kcN = (Mn + 31) >> 5;
    for (int kc = 0; kc < kcN; ++kc) {
      int ko = kc * 32 + quad * 8;
      short8 ah = *(const short8*)(s_wh + col * 264 + ko);
      short8 al = *(const short8*)(s_wl + col * 264 + ko);
      int jt = kc * 2 + (quad >> 1);
      size_t sb = (size_t)jt * (DM * 16) + (quad & 1) * 8;
      short8 bh0 = *(const short8*)(vbh + sb + d0 * 16);
      short8 bl0 = *(const short8*)(vbl + sb + d0 * 16);
      short8 bh1 = *(const short8*)(vbh + sb + d1 * 16);
      short8 bl1 = *(const short8*)(vbl + sb + d1 * 16);
      acc0 = MFMA_BF16(ah, bh0, acc0);
      acc0 = MFMA_BF16(ah, bl0, acc0);
      acc0 = MFMA_BF16(al, bh0, acc0);
      acc1 = MFMA_BF16(ah, bh1, acc1);
      acc1 = MFMA_BF16(ah, bl1, acc1);
      acc1 = MFMA_BF16(al, bh1, acc1);
    }
  }

  // store: D rows quad*4+reg, cols d0/d1; disjoint across blocks
  #pragma unroll
  for (int reg = 0; reg < 4; ++reg) {
    int rr = quad * 4 + reg;
    int iw = r0 + rr;
    if (iw < Me) {
      int pos = idx[e * C + iw];
      float* orow = out + ((size_t)b * P + pos) * DM;
      orow[d0] = acc0[reg];
      orow[d1] = acc1[reg];
    }
  }
}

// ---------------- launch ----------------
extern "C" void kernel_launch(void* const* d_in, const int* in_sizes, int n_in,
                              void* d_out, int out_size, void* d_ws, size_t ws_size,
                              hipStream_t stream) {
  const float* tokens = (const float*)d_in[0];
  const float* fingerprints = (const float*)d_in[1];
  const float* alpha = (const float*)d_in[2];
  const float* gw1 = (const float*)d_in[3];
  const float* gb1 = (const float*)d_in[4];
  const float* gw2 = (const float*)d_in[5];
  const float* gb2 = (const float*)d_in[6];
  const float* qw = (const float*)d_in[7];
  const float* kw = (const float*)d_in[8];
  const float* vw = (const float*)d_in[9];
  const float* penta = (const float*)d_in[10];
  const float* fusw = (const float*)d_in[11];
  const float* temp = (const float*)d_in[12];
  float* out = (float*)d_out;

  float* ws = (float*)d_ws;
  float* Qa = ws;                                   // E*5*B*C
  float* Ka = Qa + (size_t)E * 5 * B * C;
  float* kmx = Ka + (size_t)E * 5 * B * C;          // E*5*B*NCH
  float* kmn = kmx + (size_t)E * 5 * B * NCH;
  unsigned short* qkdT_h = (unsigned short*)(kmn + (size_t)E * 5 * B * NCH);
  unsigned short* qkdT_l = qkdT_h + (size_t)E * 16 * 64;
  unsigned short* vwT_h = qkdT_l + (size_t)E * 16 * 64;
  unsigned short* vwT_l = vwT_h + (size_t)E * S * DM;
  unsigned short* Vt_h = vwT_l + (size_t)E * S * DM;       // E*B*DM*C (slabbed)
  unsigned short* Vt_l = Vt_h + (size_t)E * B * DM * C;
  int* idx = (int*)(Vt_l + (size_t)E * B * DM * C);
  int* counts = idx + (size_t)E * C;

  RoutesArg R;
  compute_routes(R.nb);

  hipMemsetAsync(d_out, 0, (size_t)out_size * sizeof(float), stream);
  k_setup<<<dim3(E, 2), dim3(256), 0, stream>>>(fingerprints, qw, kw, penta, temp, vw,
                                                idx, counts, qkdT_h, qkdT_l, vwT_h, vwT_l);
  k_p1<<<dim3(E, B, NCH), dim3(256), 0, stream>>>(tokens, alpha, gw1, gb1, gw2, gb2,
                                                  qkdT_h, qkdT_l, vwT_h, vwT_l,
                                                  idx, counts, Qa, Ka, Vt_h, Vt_l,
                                                  kmx, kmn);
  k_p2v<<<dim3(E, B, NCH), dim3(256), 0, stream>>>(Qa, Ka, Vt_h, Vt_l, kmx, kmn,
                                                   idx, counts, fusw, out, R);
}

// Round 6
// 190.720 us; speedup vs baseline: 1.2956x; 1.0958x over previous
//
#include <hip/hip_runtime.h>
#include <cfloat>
#include <math.h>

#define E 16
#define DFULL 1024
#define DM 128
#define S 64
#define P 2048
#define B 8
#define C 256
#define W 3
#define H 16
#define RQ 16   /* rows per block chunk */
#define NCH 16  /* row chunks per (e,b) */
#define LOG2E 1.4426950408889634f
#define WST 272 /* s_w stride in u16: 16B-aligned rows, low-order banks */

typedef __attribute__((ext_vector_type(8))) short short8;
typedef __attribute__((ext_vector_type(4))) float f32x4;
#define MFMA_BF16(a, b, c) __builtin_amdgcn_mfma_f32_16x16x32_bf16((a), (b), (c), 0, 0, 0)

struct RoutesArg { int nb[E][W]; };

// ---------------- host: replicate _expert_routes() exactly ----------------
static void compute_routes(int r[E][W]) {
  float coords[E];
  for (int i = 0; i < E; ++i) {
    double x = (double)i / (double)(E - 1);
    if (x < 1e-06) x = 1e-06;
    if (x > 1.0 - 1e-06) x = 1.0 - 1e-06;
    double val = 0.0, factor = 0.5;
    for (int k = 0; k < 8; ++k) {
      x *= 3.0;
      int d = (int)x;
      x -= (double)d;
      if (d == 2) val += factor;
      factor *= 0.5;
    }
    coords[i] = (float)val;
  }
  for (int e = 0; e < E; ++e) {
    float de[E];
    for (int i = 0; i < E; ++i) de[i] = fabsf(coords[i] - coords[e]);
    bool used[E] = {false};
    for (int w = 0; w < W; ++w) {
      int best = -1; float bd = FLT_MAX;
      for (int i = 0; i < E; ++i)
        if (!used[i] && de[i] < bd) { bd = de[i]; best = i; }  // strict < = stable
      used[best] = true;
      r[e][w] = best;
    }
  }
}

__device__ __forceinline__ unsigned short bfhi(float x) {
  return (unsigned short)(__float_as_uint(x) >> 16);  // truncation split
}
__device__ __forceinline__ float bf2f(unsigned short h) {
  return __uint_as_float(((unsigned)h) << 16);
}
__device__ __forceinline__ float gelu_tanh(float x) {
  float x3 = x * x * x;
  return 0.5f * x * (1.0f + tanhf(0.7978845608028654f * (x + 0.044715f * x3)));
}
__device__ __forceinline__ float sigmoidf_(float x) {
  return 1.0f / (1.0f + __expf(-x));
}

// ---------------- K0: dispatch + bf16 weight planes (grid E x 2) ----------------
__global__ __launch_bounds__(256) void k_setup(
    const float* __restrict__ fp, const float* __restrict__ qw,
    const float* __restrict__ kw, const float* __restrict__ penta,
    const float* __restrict__ temp, const float* __restrict__ vw,
    int* __restrict__ idx, int* __restrict__ counts,
    unsigned short* __restrict__ qkdT_h, unsigned short* __restrict__ qkdT_l,
    unsigned short* __restrict__ vwT_h, unsigned short* __restrict__ vwT_l) {
  int e = blockIdx.x, t = threadIdx.x;
  __shared__ float s_tr[DM * 65];  // transpose staging (pad 65, conflict-free)
  if (blockIdx.y == 1) {
    // vwT: [e][d(128)][s(64)] hi/lo; both global sides coalesced via LDS
    const float* vwe = vw + (size_t)e * S * DM;
    for (int u = t; u < S * DM; u += 256) {
      int s = u >> 7, d = u & 127;           // coalesced read (u = s*128+d)
      s_tr[d * 65 + s] = vwe[u];
    }
    __syncthreads();
    for (int u = t; u < S * DM; u += 256) {  // u = d*64+s -> coalesced write
      int d = u >> 6, s = u & 63;
      float f = s_tr[d * 65 + s];
      unsigned short h = bfhi(f), l = bfhi(f - bf2f(h));
      vwT_h[(size_t)e * 8192 + u] = h;
      vwT_l[(size_t)e * 8192 + u] = l;
    }
    return;
  }
  // ---- dispatch ----
  {
    float lo = (float)e * 0.0625f, hi = (float)(e + 1) * 0.0625f;
    bool last = (e == E - 1);
    int p0 = t * 8;
    int m[8]; int ls = 0;
    #pragma unroll
    for (int k = 0; k < 8; ++k) {
      float f = fp[p0 + k];
      bool mm = (f >= lo) && (last ? (f <= hi) : (f < hi));
      m[k] = mm ? 1 : 0;
      ls += m[k];
    }
    __shared__ int sc[256];
    sc[t] = ls;
    __syncthreads();
    for (int o = 1; o < 256; o <<= 1) {
      int v = (t >= o) ? sc[t - o] : 0;
      __syncthreads();
      sc[t] += v;
      __syncthreads();
    }
    int incl = sc[t];
    int M = sc[255];
    int r = incl - ls;
    #pragma unroll
    for (int k = 0; k < 8; ++k) {
      if (m[k]) {
        if (r < C) idx[e * C + r] = p0 + k;
        r++;
      }
    }
    if (t == 0) counts[e] = (M < C) ? M : C;
  }
  __syncthreads();
  // ---- qkdT (folded penta-norm + 1/T), [e][c(16)][s(64)] hi/lo ----
  __shared__ float s_rn[5];
  if (t < 5) {
    const float* pv = penta + (e * 5 + t) * DM;
    float ss = 0.f;
    for (int d = 0; d < DM; ++d) ss += pv[d] * pv[d];
    s_rn[t] = 1.0f / sqrtf(ss);
  }
  __syncthreads();
  float invT = 1.0f / temp[0];
  int s = t & 63, cg = t >> 6;
  for (int c = cg; c < 10; c += 4) {
    int v = c % 5;
    bool isq = (c < 5);
    const float* wrow = (isq ? qw : kw) + ((size_t)e * S + s) * DM;
    const float* pv = penta + (e * 5 + v) * DM;
    float acc = 0.f;
    #pragma unroll
    for (int d4 = 0; d4 < DM / 4; ++d4) {
      float4 a = ((const float4*)wrow)[d4];
      float4 p = ((const float4*)pv)[d4];
      acc += a.x * p.x + a.y * p.y + a.z * p.z + a.w * p.w;
    }
    float val = acc * s_rn[v] * (isq ? invT : 1.0f);
    unsigned short h = bfhi(val), l = bfhi(val - bf2f(h));
    qkdT_h[(e * 16 + c) * 64 + s] = h;
    qkdT_l[(e * 16 + c) * 64 + s] = l;
  }
  for (int c = 10 + cg; c < 16; c += 4) {  // zero-pad c=10..15
    qkdT_h[(e * 16 + c) * 64 + s] = 0;
    qkdT_l[(e * 16 + c) * 64 + s] = 0;
  }
}

// ---------------- K1: out-zero + gate + Qa/Ka (MFMA) + Vt slabs, 512 thr ----------------
__global__ __launch_bounds__(512, 8) void k_p1(
    const float* __restrict__ tokens, const float* __restrict__ alpha,
    const float* __restrict__ gw1, const float* __restrict__ gb1,
    const float* __restrict__ gw2, const float* __restrict__ gb2,
    const unsigned short* __restrict__ qkdT_h, const unsigned short* __restrict__ qkdT_l,
    const unsigned short* __restrict__ vwT_h, const unsigned short* __restrict__ vwT_l,
    const int* __restrict__ idx, const int* __restrict__ counts,
    float* __restrict__ Qa, float* __restrict__ Ka,
    unsigned short* __restrict__ Vt_h, unsigned short* __restrict__ Vt_l,
    float* __restrict__ kmx, float* __restrict__ kmn,
    float* __restrict__ out) {
  int e = blockIdx.x, b = blockIdx.y, rq = blockIdx.z;
  int t = threadIdx.x;

  // zero my disjoint 4KB slice of out (replaces memset node); must run before exit
  {
    int blk = (e * B + b) * NCH + rq;  // 0..2047; 2048*1024 = B*P*DM exactly
    if (t < 256) {
      float4 z4 = {0.f, 0.f, 0.f, 0.f};
      ((float4*)out)[(size_t)blk * 256 + t] = z4;
    }
  }

  int Me = counts[e];
  int r0 = rq * RQ;
  if (r0 >= Me) {
    if (t < 5) {
      kmx[((e * 5 + t) * B + b) * NCH + rq] = -FLT_MAX;
      kmn[((e * 5 + t) * B + b) * NCH + rq] = FLT_MAX;
    }
    return;
  }

  __shared__ float s_f[RQ * 65];
  __shared__ __align__(16) unsigned short s_fh[RQ * 72];
  __shared__ __align__(16) unsigned short s_fl[RQ * 72];
  __shared__ float s_gw1[S * H];
  __shared__ float s_gh[RQ * 8 * H];
  __shared__ float s_scl[RQ];
  __shared__ float s_kx[5 * RQ], s_kn[5 * RQ];
  __shared__ __align__(16) unsigned short s_vth[DM * 16];  // [d][row]
  __shared__ __align__(16) unsigned short s_vtl[DM * 16];

  // stage feats (16 rows x 16 float4) and gw1 (256 f4)
  if (t < 256) {
    int row = t >> 4, q4 = t & 15;
    int ii = r0 + row;
    int pos = (ii < Me) ? idx[e * C + ii] : idx[e * C];
    const float* trow = tokens + ((size_t)b * P + pos) * DFULL + e * S;
    float4 v4 = ((const float4*)trow)[q4];
    s_f[row * 65 + q4 * 4 + 0] = v4.x;
    s_f[row * 65 + q4 * 4 + 1] = v4.y;
    s_f[row * 65 + q4 * 4 + 2] = v4.z;
    s_f[row * 65 + q4 * 4 + 3] = v4.w;
    ((float4*)s_gw1)[t] = ((const float4*)(gw1 + (size_t)e * S * H))[t];
  }
  __syncthreads();

  // gate partials: 8 threads per row, 8 s each
  if (t < 128) {
    int row = t >> 3, sq = t & 7;
    float hh[H];
    #pragma unroll
    for (int j = 0; j < H; ++j) hh[j] = 0.f;
    #pragma unroll
    for (int k = 0; k < 8; ++k) {
      int s = sq * 8 + k;
      float fs = s_f[row * 65 + s];
      const float* gr = s_gw1 + s * H;
      #pragma unroll
      for (int j = 0; j < H; ++j) hh[j] += fs * gr[j];
    }
    #pragma unroll
    for (int j = 0; j < H; ++j) s_gh[(row * 8 + sq) * H + j] = hh[j];
  }
  __syncthreads();
  if (t < RQ) {
    float z = gb2[e];
    #pragma unroll
    for (int j = 0; j < H; ++j) {
      float hj = gb1[e * H + j];
      #pragma unroll
      for (int p = 0; p < 8; ++p) hj += s_gh[(t * 8 + p) * H + j];
      z += gelu_tanh(hj) * gw2[e * H + j];
    }
    float aw = sigmoidf_(alpha[e]);
    s_scl[t] = sigmoidf_(z) * aw + (1.0f - aw);
  }
  __syncthreads();
  // scale + split-bf16 convert (4 elems/thread over 256 threads)
  if (t < 256) {
    int row = t >> 4, s0 = (t & 15) * 4;
    float sc = s_scl[row];
    #pragma unroll
    for (int k = 0; k < 4; ++k) {
      float f = s_f[row * 65 + s0 + k] * sc;
      unsigned short h = bfhi(f), l = bfhi(f - bf2f(h));
      s_fh[row * 72 + s0 + k] = h;
      s_fl[row * 72 + s0 + k] = l;
    }
  }
  __syncthreads();

  int L = t & 63, wv = t >> 6, quad = L >> 4, col = L & 15;

  // V = feats @ v_w via MFMA: one 16-d fragment per wave (8 waves = 128 d)
  {
    const unsigned short* vTh = vwT_h + (size_t)e * 8192;
    const unsigned short* vTl = vwT_l + (size_t)e * 8192;
    f32x4 va = {0.f, 0.f, 0.f, 0.f};
    int d0 = wv * 16 + col;
    #pragma unroll
    for (int kc = 0; kc < 2; ++kc) {
      int ko = kc * 32 + quad * 8;
      short8 ah = *(const short8*)(s_fh + col * 72 + ko);
      short8 al = *(const short8*)(s_fl + col * 72 + ko);
      short8 bh = *(const short8*)(vTh + d0 * 64 + ko);
      short8 bl = *(const short8*)(vTl + d0 * 64 + ko);
      va = MFMA_BF16(ah, bh, va);
      va = MFMA_BF16(ah, bl, va);
      va = MFMA_BF16(al, bh, va);
    }
    #pragma unroll
    for (int reg = 0; reg < 4; ++reg) {
      int row = quad * 4 + reg;
      float f0 = va[reg];
      unsigned short h0 = bfhi(f0), l0 = bfhi(f0 - bf2f(h0));
      s_vth[d0 * 16 + row] = h0;
      s_vtl[d0 * 16 + row] = l0;
    }
  }

  // Qa/Ka = feats @ qkd^T via MFMA (wave 0; N=16 covers c=0..9 + pad)
  if (wv == 0) {
    const unsigned short* qTh = qkdT_h + e * 16 * 64;
    const unsigned short* qTl = qkdT_l + e * 16 * 64;
    f32x4 qa = {0.f, 0.f, 0.f, 0.f};
    #pragma unroll
    for (int kc = 0; kc < 2; ++kc) {
      int ko = kc * 32 + quad * 8;
      short8 ah = *(const short8*)(s_fh + col * 72 + ko);
      short8 al = *(const short8*)(s_fl + col * 72 + ko);
      short8 bh = *(const short8*)(qTh + col * 64 + ko);
      short8 bl = *(const short8*)(qTl + col * 64 + ko);
      qa = MFMA_BF16(ah, bh, qa);
      qa = MFMA_BF16(ah, bl, qa);
      qa = MFMA_BF16(al, bh, qa);
    }
    #pragma unroll
    for (int reg = 0; reg < 4; ++reg) {
      int row = quad * 4 + reg;
      int ii = r0 + row;
      float val = qa[reg];
      if (col < 5) {
        if (ii < Me) Qa[((e * 5 + col) * B + b) * C + ii] = val;
      } else if (col < 10) {
        int v = col - 5;
        if (ii < Me) Ka[((e * 5 + v) * B + b) * C + ii] = val;
        s_kx[v * RQ + row] = (ii < Me) ? val : -FLT_MAX;
        s_kn[v * RQ + row] = (ii < Me) ? val : FLT_MAX;
      }
    }
  }
  __syncthreads();
  if (t < 5) {
    float mx = -FLT_MAX, mn = FLT_MAX;
    for (int r = 0; r < RQ; ++r) {
      mx = fmaxf(mx, s_kx[t * RQ + r]);
      mn = fminf(mn, s_kn[t * RQ + r]);
    }
    kmx[((e * 5 + t) * B + b) * NCH + rq] = mx;
    kmn[((e * 5 + t) * B + b) * NCH + rq] = mn;
  }
  // Vt slab store: [e][b][js(8j)][d(128)][8] -- both sides coalesced
  if (t < 256) {
    size_t base = (size_t)(e * B + b) * (DM * C);
    int jsl = t >> 7, d = t & 127;
    size_t dst = base + ((size_t)(rq * 2 + jsl) * DM + d) * 8;
    int src = d * 16 + jsl * 8;
    *(short8*)(Vt_h + dst) = *(const short8*)(s_vth + src);
    *(short8*)(Vt_l + dst) = *(const short8*)(s_vtl + src);
  }
}

// ---------------- K2: l-pass + w + MFMA vs slab Vt, 512 thr ----------------
__global__ __launch_bounds__(512, 8) void k_p2v(
    const float* __restrict__ Qa, const float* __restrict__ Ka,
    const unsigned short* __restrict__ Vt_h, const unsigned short* __restrict__ Vt_l,
    const float* __restrict__ kmx, const float* __restrict__ kmn,
    const int* __restrict__ idx, const int* __restrict__ counts,
    const float* __restrict__ fusw, float* __restrict__ out, RoutesArg R) {
  int e = blockIdx.x, b = blockIdx.y, rq = blockIdx.z;
  int t = threadIdx.x;
  int Me = counts[e];
  int r0 = rq * RQ;
  if (r0 >= Me) return;

  __shared__ float s_ka[5 * C];                             // 5 KB, per-neighbor
  __shared__ __align__(16) unsigned short s_wh[RQ * WST];   // 8.7 KB
  __shared__ __align__(16) unsigned short s_wl[RQ * WST];
  __shared__ float s_lp[32 * 5 * RQ];                       // 10 KB
  __shared__ float s_KX[5], s_KN[5];
  __shared__ float s_l[5 * RQ];
  float* s_red = (float*)s_wh;  // overlay: 480 floats, dead before phase A

  int nbs[3] = {R.nb[e][0], R.nb[e][1], R.nb[e][2]};
  int Mns[3] = {counts[nbs[0]], counts[nbs[1]], counts[nbs[2]]};
  int row = t & 15, jq = t >> 4;  // jq 0..31
  int ii = r0 + row;

  // cooperative kmx/kmn reduce (one global load per thread)
  if (t < 240) {
    int v = t / 48, rr = t % 48, n = rr >> 4, k = rr & 15;
    int base = ((nbs[n] * 5 + v) * B + b) * NCH + k;
    s_red[t] = kmx[base];
    s_red[240 + t] = kmn[base];
  }
  __syncthreads();
  if (t < 5) {
    float KX = -FLT_MAX, KN = FLT_MAX;
    for (int u = 0; u < 48; ++u) {
      KX = fmaxf(KX, s_red[t * 48 + u]);
      KN = fminf(KN, s_red[240 + t * 48 + u]);
    }
    s_KX[t] = KX; s_KN[t] = KN;
  }
  __syncthreads();

  // per-row q2/m2 (exact row max of scores, log2e-folded)
  float q2[5], m2[5];
  #pragma unroll
  for (int v = 0; v < 5; ++v) {
    float qv = Qa[(((size_t)e * 5 + v) * B + b) * C + ii];
    q2[v] = qv * LOG2E;
    m2[v] = ((qv > 0.f) ? qv * s_KX[v] : qv * s_KN[v]) * LOG2E;
  }

  // l-pass: per-neighbor ka staging, 32-way j split
  float lp[5] = {0.f, 0.f, 0.f, 0.f, 0.f};
  for (int n = 0; n < 3; ++n) {
    __syncthreads();  // previous ka fully consumed
    if (t < 320) {
      int v = t >> 6, off = t & 63;
      ((float4*)s_ka)[v * 64 + off] =
          ((const float4*)(Ka + (((size_t)nbs[n] * 5 + v) * B + b) * C))[off];
    }
    __syncthreads();
    int Mn = Mns[n];
    for (int j = jq; j < Mn; j += 32) {
      #pragma unroll
      for (int v = 0; v < 5; ++v)
        lp[v] += exp2f(fmaf(q2[v], s_ka[v * C + j], -m2[v]));
    }
  }
  #pragma unroll
  for (int v = 0; v < 5; ++v) s_lp[(jq * 5 + v) * RQ + row] = lp[v];
  __syncthreads();
  if (t < 80) {
    int v = t >> 4, rw = t & 15;
    float l = 0.f;
    #pragma unroll
    for (int g = 0; g < 32; ++g) l += s_lp[(g * 5 + v) * RQ + rw];
    s_l[v * RQ + rw] = l;
  }
  __syncthreads();

  // c2 = log2(wdir_v / l) - m2  (fold cl into exp2 arg)
  float fw[5];
  #pragma unroll
  for (int v = 0; v < 5; ++v) fw[v] = fusw[v];
  float fmx = fw[0];
  #pragma unroll
  for (int v = 1; v < 5; ++v) fmx = fmaxf(fmx, fw[v]);
  float fsum = 0.f;
  #pragma unroll
  for (int v = 0; v < 5; ++v) { fw[v] = __expf(fw[v] - fmx); fsum += fw[v]; }
  float c2[5];
  #pragma unroll
  for (int v = 0; v < 5; ++v) {
    float cl = (fw[v] / fsum) / s_l[v * RQ + row];
    c2[v] = __log2f(cl) - m2[v];
  }

  int L = t & 63, wv = t >> 6, quad = L >> 4, col = L & 15;
  int d0 = wv * 16 + col;  // one 16-d fragment per wave
  f32x4 acc = {0.f, 0.f, 0.f, 0.f};

  for (int n = 0; n < 3; ++n) {
    int ne = nbs[n], Mn = Mns[n];
    __syncthreads();  // prev phase-B s_w reads + prev ka reads done
    if (t < 320) {
      int v = t >> 6, off = t & 63;
      ((float4*)s_ka)[v * 64 + off] =
          ((const float4*)(Ka + (((size_t)ne * 5 + v) * B + b) * C))[off];
    }
    __syncthreads();
    // phase A: combined weights, 8 j per thread, b128 writes
    {
      short8 wh8, wl8;
      #pragma unroll
      for (int k2 = 0; k2 < 8; ++k2) {
        int jj = jq * 8 + k2;
        float ww = 0.f;
        if (jj < Mn) {
          #pragma unroll
          for (int v = 0; v < 5; ++v)
            ww += exp2f(fmaf(q2[v], s_ka[v * C + jj], c2[v]));
        }
        unsigned short h = bfhi(ww), l = bfhi(ww - bf2f(h));
        wh8[k2] = (short)h;
        wl8[k2] = (short)l;
      }
      *(short8*)(s_wh + row * WST + jq * 8) = wh8;
      *(short8*)(s_wl + row * WST + jq * 8) = wl8;
    }
    __syncthreads();
    // phase B: MFMA, A = w (LDS), B = Vt slabs (global, line-perfect)
    const unsigned short* vbh = Vt_h + (size_t)(ne * B + b) * (DM * C);
    const unsigned short* vbl = Vt_l + (size_t)(ne * B + b) * (DM * C);
    int kcN = (Mn + 31) >> 5;
    for (int kc = 0; kc < kcN; ++kc) {
      int ko = kc * 32 + quad * 8;
      short8 ah = *(const short8*)(s_wh + col * WST + ko);
      short8 al = *(const short8*)(s_wl + col * WST + ko);
      size_t sb = ((size_t)(kc * 4 + quad) * DM + d0) * 8;
      short8 bh = *(const short8*)(vbh + sb);
      short8 bl = *(const short8*)(vbl + sb);
      acc = MFMA_BF16(ah, bh, acc);
      acc = MFMA_BF16(ah, bl, acc);
      acc = MFMA_BF16(al, bh, acc);
    }
  }

  // store: D rows quad*4+reg at col d0; disjoint across blocks
  #pragma unroll
  for (int reg = 0; reg < 4; ++reg) {
    int rr = quad * 4 + reg;
    int iw = r0 + rr;
    if (iw < Me) {
      int pos = idx[e * C + iw];
      out[((size_t)b * P + pos) * DM + d0] = acc[reg];
    }
  }
}

// ---------------- launch ----------------
extern "C" void kernel_launch(void* const* d_in, const int* in_sizes, int n_in,
                              void* d_out, int out_size, void* d_ws, size_t ws_size,
                              hipStream_t stream) {
  const float* tokens = (const float*)d_in[0];
  const float* fingerprints = (const float*)d_in[1];
  const float* alpha = (const float*)d_in[2];
  const float* gw1 = (const float*)d_in[3];
  const float* gb1 = (const float*)d_in[4];
  const float* gw2 = (const float*)d_in[5];
  const float* gb2 = (const float*)d_in[6];
  const float* qw = (const float*)d_in[7];
  const float* kw = (const float*)d_in[8];
  const float* vw = (const float*)d_in[9];
  const float* penta = (const float*)d_in[10];
  const float* fusw = (const float*)d_in[11];
  const float* temp = (const float*)d_in[12];
  float* out = (float*)d_out;

  float* ws = (float*)d_ws;
  float* Qa = ws;                                   // E*5*B*C
  float* Ka = Qa + (size_t)E * 5 * B * C;
  float* kmx = Ka + (size_t)E * 5 * B * C;          // E*5*B*NCH
  float* kmn = kmx + (size_t)E * 5 * B * NCH;
  unsigned short* qkdT_h = (unsigned short*)(kmn + (size_t)E * 5 * B * NCH);
  unsigned short* qkdT_l = qkdT_h + (size_t)E * 16 * 64;
  unsigned short* vwT_h = qkdT_l + (size_t)E * 16 * 64;
  unsigned short* vwT_l = vwT_h + (size_t)E * S * DM;
  unsigned short* Vt_h = vwT_l + (size_t)E * S * DM;       // E*B*DM*C (slabbed)
  unsigned short* Vt_l = Vt_h + (size_t)E * B * DM * C;
  int* idx = (int*)(Vt_l + (size_t)E * B * DM * C);
  int* counts = idx + (size_t)E * C;

  RoutesArg R;
  compute_routes(R.nb);

  k_setup<<<dim3(E, 2), dim3(256), 0, stream>>>(fingerprints, qw, kw, penta, temp, vw,
                                                idx, counts, qkdT_h, qkdT_l, vwT_h, vwT_l);
  k_p1<<<dim3(E, B, NCH), dim3(512), 0, stream>>>(tokens, alpha, gw1, gb1, gw2, gb2,
                                                  qkdT_h, qkdT_l, vwT_h, vwT_l,
                                                  idx, counts, Qa, Ka, Vt_h, Vt_l,
                                                  kmx, kmn, out);
  k_p2v<<<dim3(E, B, NCH), dim3(512), 0, stream>>>(Qa, Ka, Vt_h, Vt_l, kmx, kmn,
                                                   idx, counts, fusw, out, R);
}